// Round 15
// baseline (263.292 us; speedup 1.0000x reference)
//
#include <hip/hip_runtime.h>

#define DIM 128
#define SLOTS 64

typedef __attribute__((ext_vector_type(8))) short bf16x8;
typedef __attribute__((ext_vector_type(4))) float f32x4;
typedef __attribute__((ext_vector_type(2))) float f32x2;
typedef unsigned short u16;
typedef unsigned int u32;
typedef unsigned long long u64;

__device__ __forceinline__ float bf2f(u32 u) {
    return __builtin_bit_cast(float, u << 16);
}
__device__ __forceinline__ u16 f2bf(float f) {
    u32 u = __builtin_bit_cast(u32, f);
    u = (u + 0x7FFFu + ((u >> 16) & 1u)) >> 16;   // RNE
    return (u16)u;
}
__device__ __forceinline__ u32 pack2bf(float a, float b) {
    return (u32)f2bf(a) | ((u32)f2bf(b) << 16);
}

// ---------------- fused setup: deg/fill atomics (4 edges/thread) + bucket scatter + x->bf16 + Wt x3 ----------------
// bucket lo32 = (c << 8) | et  -> byte offset into xb is (lo & 0xFFFFFF00), type is (lo & 3)

__global__ __launch_bounds__(256) void k_setup(const int* __restrict__ row, const int* __restrict__ col,
                                               const int* __restrict__ et, const float* __restrict__ ew,
                                               int E, int* __restrict__ deg, int* __restrict__ fill,
                                               u64* __restrict__ ep,
                                               const float* __restrict__ x, u16* __restrict__ xb, int nx4,
                                               const float* __restrict__ W1, const float* __restrict__ W2,
                                               const float* __restrict__ W3,
                                               u16* __restrict__ Wt1, u16* __restrict__ Wt2,
                                               u16* __restrict__ Wt3, int nEb, int nXb) {
    int b = blockIdx.x, tid = threadIdx.x;
    if (b < nEb) {
        int e0 = (b * 256 + tid) * 4;
        #pragma unroll
        for (int i = 0; i < 4; i++) {
            int e = e0 + i;
            if (e < E) {
                int r = row[e], c = col[e];
                atomicAdd(&deg[c], 1);                    // in-degree (col counts)
                int pos = atomicAdd(&fill[r], 1);         // bucket slot for row
                if (pos < SLOTS)
                    ep[(size_t)r * SLOTS + pos] =
                        ((u64)__builtin_bit_cast(u32, ew[e]) << 32) | (u32)((c << 8) | et[e]);
            }
        }
    } else if (b < nEb + nXb) {
        int i = (b - nEb) * 256 + tid;
        if (i < nx4) {
            float4 v = ((const float4*)x)[i];
            ushort4 o;
            o.x = f2bf(v.x); o.y = f2bf(v.y); o.z = f2bf(v.z); o.w = f2bf(v.w);
            ((ushort4*)xb)[i] = o;
        }
    } else {
        int b2 = b - nEb - nXb;                    // 0..767
        const float* W = b2 < 256 ? W1 : (b2 < 512 ? W2 : W3);
        u16* Wt = b2 < 256 ? Wt1 : (b2 < 512 ? Wt2 : Wt3);
        int o = (b2 & 255) * 256 + tid;            // 0..65535
        // natural fragment order: o = chunk*1024 + col*8 + s, k = chunk*8 + s = t*128 + i
        int chunk = o >> 10;
        int c = (o >> 3) & 127;
        int k = chunk * 8 + (o & 7);
        Wt[o] = f2bf(W[(k >> 7) * 16384 + (k & 127) * 128 + c]);
    }
}

// ---------------- k_norm: fold full norm (rsqrt inline) into bucket weights + zero-pad to x16 ----------------

__global__ __launch_bounds__(256) void k_norm(const int* __restrict__ fill,
                                              const int* __restrict__ deg,
                                              u64* __restrict__ ep, int N) {
    int wid = threadIdx.x >> 6, lane = threadIdx.x & 63;
    int n = blockIdx.x * 4 + wid;
    if (n >= N) return;
    int cnt = fill[n]; if (cnt > SLOTS) cnt = SLOTS;
    int padded = (cnt + 15) & ~15;
    int dgn = deg[n];
    float dn = dgn > 0 ? rsqrtf((float)dgn) : 0.f;
    u64* eb = ep + (size_t)n * SLOTS;
    if (lane < cnt) {
        u64 q = eb[lane];
        u32 lo = (u32)q;
        int dgc = deg[lo >> 8];
        float dc = dgc > 0 ? rsqrtf((float)dgc) : 0.f;
        float wgt = __builtin_bit_cast(float, (u32)(q >> 32)) * dn * dc;
        eb[lane] = ((u64)__builtin_bit_cast(u32, wgt) << 32) | lo;
    } else if (lane < padded) {
        eb[lane] = 0;   // zero weight, col 0, type 0
    }
}

// ---------------- fused layer: register-resident bucket -> 16-deep gather batches -> LDS -> MFMA ----------------
// block = 1024 thr / 16 waves = 16 nodes, one node per wave. Occupancy is thread-capped at
// 32 waves/CU (hardware max), so concurrency scales only with per-wave batch depth:
// 16 gathers in flight (addresses register-resident via readlane, no memory dependence).

template <int MODE>
__global__ __launch_bounds__(1024, 2) void k_layer(const u16* __restrict__ src,
                                                   const int* __restrict__ fill,
                                                   const u64* __restrict__ ep,
                                                   const u16* __restrict__ Wt,
                                                   const float* __restrict__ bias,
                                                   const float* __restrict__ x0,
                                                   const u16* __restrict__ z1b,
                                                   const u16* __restrict__ z2b,
                                                   float* __restrict__ outf,
                                                   u16* __restrict__ outb, int N) {
    __shared__ u16 sA[16 * 512];   // 16 KB
    int tid = threadIdx.x, wid = tid >> 6, lane = tid & 63;
    int n0 = blockIdx.x * 16;
    int n = n0 + wid;

    f32x2 a0 = {0.f, 0.f}, a1 = {0.f, 0.f}, a2 = {0.f, 0.f}, a3 = {0.f, 0.f};
    int cnt = 0;
    if (n < N) {
        cnt = fill[n];
        if (cnt > SLOTS) cnt = SLOTS;
    }
    // whole bucket in registers: lane l holds slot l
    u64 myq = ep[(size_t)n * SLOTS + lane];
    u32 mylo = (u32)myq;
    u32 mywu = (u32)(myq >> 32);
    const char* xbase = (const char*)src + lane * 4;

#define RL(x, i_) ((u32)__builtin_amdgcn_readlane((int)(x), (i_)))

#define EDGE(lo_, wu_, v_) { \
        float w_  = __builtin_bit_cast(float, (u32)(wu_)); \
        f32x2 vv_; \
        vv_[0] = __builtin_bit_cast(float, (v_) << 16); \
        vv_[1] = __builtin_bit_cast(float, (v_) & 0xFFFF0000u); \
        u32 t_ = (u32)(lo_) & 3u; \
        float w0_ = t_ == 0u ? w_ : 0.f; \
        float w1_ = t_ == 1u ? w_ : 0.f; \
        float w2_ = t_ == 2u ? w_ : 0.f; \
        float w3_ = t_ == 3u ? w_ : 0.f; \
        a0 = __builtin_elementwise_fma(vv_, (f32x2){w0_, w0_}, a0); \
        a1 = __builtin_elementwise_fma(vv_, (f32x2){w1_, w1_}, a1); \
        a2 = __builtin_elementwise_fma(vv_, (f32x2){w2_, w2_}, a2); \
        a3 = __builtin_elementwise_fma(vv_, (f32x2){w3_, w3_}, a3); }

    // buckets zero-padded to multiple of 16 -> unmasked 16-deep batches
    for (int j = 0; j < cnt; j += 16) {
        u32 lo[16], wu[16], v[16];
        #pragma unroll
        for (int i = 0; i < 16; i++) {
            lo[i] = RL(mylo, j + i);
            wu[i] = RL(mywu, j + i);
        }
        #pragma unroll
        for (int i = 0; i < 16; i++)
            v[i] = *(const u32*)(xbase + (lo[i] & 0xFFFFFF00u));
        #pragma unroll
        for (int i = 0; i < 16; i++)
            EDGE(lo[i], wu[i], v[i]);
    }
#undef EDGE
#undef RL

    // LDS store: row = wid (node), k = t*128 + 2*lane; swizzle byte ^= (row&7)<<4
    {
        u32 X = (u32)((wid & 7) << 4);
        char* base = (char*)sA + wid * 1024;
        *(u32*)(base + ((lane * 4 + 0  ) ^ X)) = pack2bf(a0[0], a0[1]);
        *(u32*)(base + ((lane * 4 + 256) ^ X)) = pack2bf(a1[0], a1[1]);
        *(u32*)(base + ((lane * 4 + 512) ^ X)) = pack2bf(a2[0], a2[1]);
        *(u32*)(base + ((lane * 4 + 768) ^ X)) = pack2bf(a3[0], a3[1]);
    }
    __syncthreads();

    // MFMA: [16,512] @ [512,128]; waves 0..7 -> col tile wid*16
    if (wid < 8) {
        int lr = lane & 15, lk = lane >> 4;
        u32 X = (u32)((lr & 7) << 4);
        const char* ab = (const char*)sA + lr * 1024;
        const u16* bb = Wt + lk * 1024 + (wid * 16 + lr) * 8;
        f32x4 acc = {};
        #pragma unroll
        for (int ks = 0; ks < 16; ks++) {
            bf16x8 af = *(const bf16x8*)(ab + ((ks * 64 + lk * 16) ^ X));
            bf16x8 bfv = *(const bf16x8*)(bb + ks * 4096);
            acc = __builtin_amdgcn_mfma_f32_16x16x32_bf16(af, bfv, acc, 0, 0, 0);
        }

        // epilogue: col = lane&15 (+tile), row = (lane>>4)*4 + r
        int colg = wid * 16 + lr;
        float bv = bias[colg];
        #pragma unroll
        for (int r = 0; r < 4; r++) {
            int nn = n0 + lk * 4 + r;
            if (nn < N) {
                size_t idx = (size_t)nn * DIM + colg;
                float v = acc[r] + bv;
                v = v > 0.f ? v : 0.01f * v;
                if (MODE == 1)
                    outf[idx] = 0.25f * (x0[idx] + bf2f(z1b[idx]) + bf2f(z2b[idx]) + v);
                else
                    outb[idx] = f2bf(v);
            }
        }
    }
}

// ---------------- launch ----------------

extern "C" void kernel_launch(void* const* d_in, const int* in_sizes, int n_in,
                              void* d_out, int out_size, void* d_ws, size_t ws_size,
                              hipStream_t stream) {
    const float* x     = (const float*)d_in[0];
    const int*   eidx  = (const int*)d_in[1];
    const int*   etype = (const int*)d_in[2];
    const float* eattr = (const float*)d_in[3];
    const float* W1 = (const float*)d_in[4];
    const float* b1 = (const float*)d_in[5];
    const float* W2 = (const float*)d_in[6];
    const float* b2 = (const float*)d_in[7];
    const float* W3 = (const float*)d_in[8];
    const float* b3 = (const float*)d_in[9];

    const int E = in_sizes[2];
    const int N = in_sizes[0] / DIM;
    const int* row = eidx;
    const int* col = eidx + E;

    char* w = (char*)d_ws;
    size_t off = 0;
    auto alloc = [&](size_t bytes) { size_t o = off; off = (off + bytes + 255) & ~255ULL; return o; };
    size_t deg_off = alloc((size_t)N * 4);
    int*   deg  = (int*)(w + deg_off);
    int*   fill = (int*)(w + alloc((size_t)N * 4));
    size_t zero_bytes = off - deg_off;
    u64*   ep   = (u64*)(w + alloc((size_t)N * SLOTS * 8));
    u16*   xb   = (u16*)(w + alloc((size_t)N * DIM * 2));
    u16*   z1b  = (u16*)(w + alloc((size_t)N * DIM * 2));
    u16*   z2b  = (u16*)(w + alloc((size_t)N * DIM * 2));
    u16*   Wt1  = (u16*)(w + alloc(65536 * 2));
    u16*   Wt2  = (u16*)(w + alloc(65536 * 2));
    u16*   Wt3  = (u16*)(w + alloc(65536 * 2));

    hipMemsetAsync(deg, 0, zero_bytes, stream);

    int nx4 = N * DIM / 4;
    int nEb = (E + 1023) / 1024;    // 4 edges per thread
    int nXb = (nx4 + 255) / 256;

    k_setup<<<nEb + nXb + 768, 256, 0, stream>>>(row, col, etype, eattr, E, deg, fill, ep,
                                                 x, xb, nx4, W1, W2, W3, Wt1, Wt2, Wt3, nEb, nXb);
    k_norm<<<(N + 3) / 4, 256, 0, stream>>>(fill, deg, ep, N);

    int grid = (N + 15) / 16;
    k_layer<0><<<grid, 1024, 0, stream>>>(xb,  fill, ep, Wt1, b1, nullptr, nullptr, nullptr, nullptr, z1b, N);
    k_layer<0><<<grid, 1024, 0, stream>>>(z1b, fill, ep, Wt2, b2, nullptr, nullptr, nullptr, nullptr, z2b, N);
    k_layer<1><<<grid, 1024, 0, stream>>>(z2b, fill, ep, Wt3, b3, x, z1b, z2b, (float*)d_out, nullptr, N);
}

// Round 16
// 232.592 us; speedup vs baseline: 1.1320x; 1.1320x over previous
//
#include <hip/hip_runtime.h>

#define DIM 128
#define SLOTS 64

typedef __attribute__((ext_vector_type(8))) short bf16x8;
typedef __attribute__((ext_vector_type(4))) float f32x4;
typedef __attribute__((ext_vector_type(2))) float f32x2;
typedef unsigned short u16;
typedef unsigned int u32;
typedef unsigned long long u64;

__device__ __forceinline__ float bf2f(u32 u) {
    return __builtin_bit_cast(float, u << 16);
}
__device__ __forceinline__ u16 f2bf(float f) {
    u32 u = __builtin_bit_cast(u32, f);
    u = (u + 0x7FFFu + ((u >> 16) & 1u)) >> 16;   // RNE
    return (u16)u;
}
__device__ __forceinline__ u32 pack2bf(float a, float b) {
    return (u32)f2bf(a) | ((u32)f2bf(b) << 16);
}

// ---------------- fused setup: deg/fill atomics (4 edges/thread) + bucket scatter + x->bf16 + Wt x3 ----------------
// bucket lo32 = (c << 8) | et  -> byte offset into xb is (lo & 0xFFFFFF00), type is (lo & 3)

__global__ __launch_bounds__(256) void k_setup(const int* __restrict__ row, const int* __restrict__ col,
                                               const int* __restrict__ et, const float* __restrict__ ew,
                                               int E, int* __restrict__ deg, int* __restrict__ fill,
                                               u64* __restrict__ ep,
                                               const float* __restrict__ x, u16* __restrict__ xb, int nx4,
                                               const float* __restrict__ W1, const float* __restrict__ W2,
                                               const float* __restrict__ W3,
                                               u16* __restrict__ Wt1, u16* __restrict__ Wt2,
                                               u16* __restrict__ Wt3, int nEb, int nXb) {
    int b = blockIdx.x, tid = threadIdx.x;
    if (b < nEb) {
        int e0 = (b * 256 + tid) * 4;
        #pragma unroll
        for (int i = 0; i < 4; i++) {
            int e = e0 + i;
            if (e < E) {
                int r = row[e], c = col[e];
                atomicAdd(&deg[c], 1);                    // in-degree (col counts)
                int pos = atomicAdd(&fill[r], 1);         // bucket slot for row
                if (pos < SLOTS)
                    ep[(size_t)r * SLOTS + pos] =
                        ((u64)__builtin_bit_cast(u32, ew[e]) << 32) | (u32)((c << 8) | et[e]);
            }
        }
    } else if (b < nEb + nXb) {
        int i = (b - nEb) * 256 + tid;
        if (i < nx4) {
            float4 v = ((const float4*)x)[i];
            ushort4 o;
            o.x = f2bf(v.x); o.y = f2bf(v.y); o.z = f2bf(v.z); o.w = f2bf(v.w);
            ((ushort4*)xb)[i] = o;
        }
    } else {
        int b2 = b - nEb - nXb;                    // 0..767
        const float* W = b2 < 256 ? W1 : (b2 < 512 ? W2 : W3);
        u16* Wt = b2 < 256 ? Wt1 : (b2 < 512 ? Wt2 : Wt3);
        int o = (b2 & 255) * 256 + tid;            // 0..65535
        // natural fragment order: o = chunk*1024 + col*8 + s, k = chunk*8 + s = t*128 + i
        int chunk = o >> 10;
        int c = (o >> 3) & 127;
        int k = chunk * 8 + (o & 7);
        Wt[o] = f2bf(W[(k >> 7) * 16384 + (k & 127) * 128 + c]);
    }
}

// ---------------- k_norm: fold full norm (rsqrt inline) into bucket weights + zero-pad to x8 ----------------

__global__ __launch_bounds__(256) void k_norm(const int* __restrict__ fill,
                                              const int* __restrict__ deg,
                                              u64* __restrict__ ep, int N) {
    int wid = threadIdx.x >> 6, lane = threadIdx.x & 63;
    int n = blockIdx.x * 4 + wid;
    if (n >= N) return;
    int cnt = fill[n]; if (cnt > SLOTS) cnt = SLOTS;
    int padded = (cnt + 7) & ~7;
    int dgn = deg[n];
    float dn = dgn > 0 ? rsqrtf((float)dgn) : 0.f;
    u64* eb = ep + (size_t)n * SLOTS;
    if (lane < cnt) {
        u64 q = eb[lane];
        u32 lo = (u32)q;
        int dgc = deg[lo >> 8];
        float dc = dgc > 0 ? rsqrtf((float)dgc) : 0.f;
        float wgt = __builtin_bit_cast(float, (u32)(q >> 32)) * dn * dc;
        eb[lane] = ((u64)__builtin_bit_cast(u32, wgt) << 32) | lo;
    } else if (lane < padded) {
        eb[lane] = 0;   // zero weight, col 0, type 0
    }
}

// ---------------- fused layer: register-resident bucket + UNIFORM-BASE gathers -> LDS -> MFMA ----------------
// block = 1024 thr / 16 waves = 16 nodes, one node per wave.
// Row offset is wave-uniform (readlane -> SGPR): form rowp = src + off on the SALU and load
// rowp[lane] (SGPR base + loop-invariant VGPR offset) -> ZERO per-edge VALU for addressing.

template <int MODE>
__global__ __launch_bounds__(1024, 2) void k_layer(const u16* __restrict__ src,
                                                   const int* __restrict__ fill,
                                                   const u64* __restrict__ ep,
                                                   const u16* __restrict__ Wt,
                                                   const float* __restrict__ bias,
                                                   const float* __restrict__ x0,
                                                   const u16* __restrict__ z1b,
                                                   const u16* __restrict__ z2b,
                                                   float* __restrict__ outf,
                                                   u16* __restrict__ outb, int N) {
    __shared__ u16 sA[16 * 512];   // 16 KB
    int tid = threadIdx.x, wid = tid >> 6, lane = tid & 63;
    int n0 = blockIdx.x * 16;
    int n = n0 + wid;

    f32x2 a0 = {0.f, 0.f}, a1 = {0.f, 0.f}, a2 = {0.f, 0.f}, a3 = {0.f, 0.f};
    int cnt = 0;
    if (n < N) {
        cnt = fill[n];
        if (cnt > SLOTS) cnt = SLOTS;
    }
    // whole bucket in registers: lane l holds slot l
    u64 myq = ep[(size_t)n * SLOTS + lane];
    u32 mylo = (u32)myq;
    u32 mywu = (u32)(myq >> 32);
    const char* srcc = (const char*)src;   // uniform base

#define RL(x, i_) ((u32)__builtin_amdgcn_readlane((int)(x), (i_)))

#define EDGE(lo_, wu_, v_) { \
        float w_  = __builtin_bit_cast(float, (u32)(wu_)); \
        f32x2 vv_; \
        vv_[0] = __builtin_bit_cast(float, (v_) << 16); \
        vv_[1] = __builtin_bit_cast(float, (v_) & 0xFFFF0000u); \
        u32 t_ = (u32)(lo_) & 3u; \
        float w0_ = t_ == 0u ? w_ : 0.f; \
        float w1_ = t_ == 1u ? w_ : 0.f; \
        float w2_ = t_ == 2u ? w_ : 0.f; \
        float w3_ = t_ == 3u ? w_ : 0.f; \
        a0 = __builtin_elementwise_fma(vv_, (f32x2){w0_, w0_}, a0); \
        a1 = __builtin_elementwise_fma(vv_, (f32x2){w1_, w1_}, a1); \
        a2 = __builtin_elementwise_fma(vv_, (f32x2){w2_, w2_}, a2); \
        a3 = __builtin_elementwise_fma(vv_, (f32x2){w3_, w3_}, a3); }

    // buckets zero-padded to multiple of 8 -> unmasked 8-deep batches; uniform-base gathers
    for (int j = 0; j < cnt; j += 8) {
        u32 lo[8], wu[8], v[8];
        #pragma unroll
        for (int i = 0; i < 8; i++) {
            lo[i] = RL(mylo, j + i);
            wu[i] = RL(mywu, j + i);
        }
        #pragma unroll
        for (int i = 0; i < 8; i++) {
            const u32* rowp = (const u32*)(srcc + (lo[i] & 0xFFFFFF00u));  // SALU add
            v[i] = rowp[lane];                                             // saddr + vgpr-lane load
        }
        #pragma unroll
        for (int i = 0; i < 8; i++)
            EDGE(lo[i], wu[i], v[i]);
    }
#undef EDGE
#undef RL

    // LDS store: row = wid (node), k = t*128 + 2*lane; swizzle byte ^= (row&7)<<4
    {
        u32 X = (u32)((wid & 7) << 4);
        char* base = (char*)sA + wid * 1024;
        *(u32*)(base + ((lane * 4 + 0  ) ^ X)) = pack2bf(a0[0], a0[1]);
        *(u32*)(base + ((lane * 4 + 256) ^ X)) = pack2bf(a1[0], a1[1]);
        *(u32*)(base + ((lane * 4 + 512) ^ X)) = pack2bf(a2[0], a2[1]);
        *(u32*)(base + ((lane * 4 + 768) ^ X)) = pack2bf(a3[0], a3[1]);
    }
    __syncthreads();

    // MFMA: [16,512] @ [512,128]; waves 0..7 -> col tile wid*16
    if (wid < 8) {
        int lr = lane & 15, lk = lane >> 4;
        u32 X = (u32)((lr & 7) << 4);
        const char* ab = (const char*)sA + lr * 1024;
        const u16* bb = Wt + lk * 1024 + (wid * 16 + lr) * 8;
        f32x4 acc = {};
        #pragma unroll
        for (int ks = 0; ks < 16; ks++) {
            bf16x8 af = *(const bf16x8*)(ab + ((ks * 64 + lk * 16) ^ X));
            bf16x8 bfv = *(const bf16x8*)(bb + ks * 4096);
            acc = __builtin_amdgcn_mfma_f32_16x16x32_bf16(af, bfv, acc, 0, 0, 0);
        }

        // epilogue: col = lane&15 (+tile), row = (lane>>4)*4 + r
        int colg = wid * 16 + lr;
        float bv = bias[colg];
        #pragma unroll
        for (int r = 0; r < 4; r++) {
            int nn = n0 + lk * 4 + r;
            if (nn < N) {
                size_t idx = (size_t)nn * DIM + colg;
                float v = acc[r] + bv;
                v = v > 0.f ? v : 0.01f * v;
                if (MODE == 1)
                    outf[idx] = 0.25f * (x0[idx] + bf2f(z1b[idx]) + bf2f(z2b[idx]) + v);
                else
                    outb[idx] = f2bf(v);
            }
        }
    }
}

// ---------------- launch ----------------

extern "C" void kernel_launch(void* const* d_in, const int* in_sizes, int n_in,
                              void* d_out, int out_size, void* d_ws, size_t ws_size,
                              hipStream_t stream) {
    const float* x     = (const float*)d_in[0];
    const int*   eidx  = (const int*)d_in[1];
    const int*   etype = (const int*)d_in[2];
    const float* eattr = (const float*)d_in[3];
    const float* W1 = (const float*)d_in[4];
    const float* b1 = (const float*)d_in[5];
    const float* W2 = (const float*)d_in[6];
    const float* b2 = (const float*)d_in[7];
    const float* W3 = (const float*)d_in[8];
    const float* b3 = (const float*)d_in[9];

    const int E = in_sizes[2];
    const int N = in_sizes[0] / DIM;
    const int* row = eidx;
    const int* col = eidx + E;

    char* w = (char*)d_ws;
    size_t off = 0;
    auto alloc = [&](size_t bytes) { size_t o = off; off = (off + bytes + 255) & ~255ULL; return o; };
    size_t deg_off = alloc((size_t)N * 4);
    int*   deg  = (int*)(w + deg_off);
    int*   fill = (int*)(w + alloc((size_t)N * 4));
    size_t zero_bytes = off - deg_off;
    u64*   ep   = (u64*)(w + alloc((size_t)N * SLOTS * 8));
    u16*   xb   = (u16*)(w + alloc((size_t)N * DIM * 2));
    u16*   z1b  = (u16*)(w + alloc((size_t)N * DIM * 2));
    u16*   z2b  = (u16*)(w + alloc((size_t)N * DIM * 2));
    u16*   Wt1  = (u16*)(w + alloc(65536 * 2));
    u16*   Wt2  = (u16*)(w + alloc(65536 * 2));
    u16*   Wt3  = (u16*)(w + alloc(65536 * 2));

    hipMemsetAsync(deg, 0, zero_bytes, stream);

    int nx4 = N * DIM / 4;
    int nEb = (E + 1023) / 1024;    // 4 edges per thread
    int nXb = (nx4 + 255) / 256;

    k_setup<<<nEb + nXb + 768, 256, 0, stream>>>(row, col, etype, eattr, E, deg, fill, ep,
                                                 x, xb, nx4, W1, W2, W3, Wt1, Wt2, Wt3, nEb, nXb);
    k_norm<<<(N + 3) / 4, 256, 0, stream>>>(fill, deg, ep, N);

    int grid = (N + 15) / 16;
    k_layer<0><<<grid, 1024, 0, stream>>>(xb,  fill, ep, Wt1, b1, nullptr, nullptr, nullptr, nullptr, z1b, N);
    k_layer<0><<<grid, 1024, 0, stream>>>(z1b, fill, ep, Wt2, b2, nullptr, nullptr, nullptr, nullptr, z2b, N);
    k_layer<1><<<grid, 1024, 0, stream>>>(z2b, fill, ep, Wt3, b3, x, z1b, z2b, (float*)d_out, nullptr, N);
}